// Round 3
// baseline (49.343 us; speedup 1.0000x reference)
//
#include <hip/hip_runtime.h>

#define NDIM 1024
#define BATCH 16
#define BCHUNK 4   // batches per thread; grid.z = BATCH/BCHUNK

typedef float fvec4 __attribute__((ext_vector_type(4)));  // native vector for nontemporal builtins

// Fused spatially-varying 3x3 filter:
//   K[p,i,j] = bias[p] + sum_{m,n} w[p,0,m,n] * image_pad[i+m, j+n]
//   y[b,i,j] = sum_{k,l} K[3k+l,i,j] * x_pad[b, i+k, j+l]
// Each thread: 4 consecutive j-pixels (float4), 1 row i, BCHUNK batches.
// Software-pipelined: batch b+1 loads issued before batch b compute,
// statically-named double buffers (no runtime-indexed arrays -> no scratch).
__global__ __launch_bounds__(256, 4) void smallsm_fused(
    const float* __restrict__ image,
    const float* __restrict__ x,
    const float* __restrict__ w,
    const float* __restrict__ bias,
    float* __restrict__ out)
{
    const int N = NDIM;
    const int tx = threadIdx.x & 15;   // 16 threads in j (x4 pixels = 64 cols)
    const int ty = threadIdx.x >> 4;   // 16 threads in i
    const int j0 = (blockIdx.x * 16 + tx) * 4;
    const int i  = blockIdx.y * 16 + ty;
    const int b0 = blockIdx.z * BCHUNK;

    const bool jm_ok = (j0 > 0);
    const bool jp_ok = (j0 + 4 < N);

    // Load a 3x6 patch (rows i-1..i+1, cols j0-1..j0+4) from a [N,N] plane.
    auto load_patch = [&](const float* __restrict__ base, float (&v)[3][6]) {
#pragma unroll
        for (int r = 0; r < 3; ++r) {
            const int row = i - 1 + r;
            const bool rv = (row >= 0) && (row < N);
            const float* rp = base + (size_t)row * N;
            if (rv) {
                const fvec4 m = *reinterpret_cast<const fvec4*>(rp + j0);
                v[r][1] = m.x; v[r][2] = m.y; v[r][3] = m.z; v[r][4] = m.w;
            } else {
                v[r][1] = 0.f; v[r][2] = 0.f; v[r][3] = 0.f; v[r][4] = 0.f;
            }
            v[r][0] = (rv && jm_ok) ? rp[j0 - 1] : 0.f;
            v[r][5] = (rv && jp_ok) ? rp[j0 + 4] : 0.f;
        }
    };

    float K[9][4];

    // Apply per-pixel kernels to one batch patch and store the float4.
    auto apply_store = [&](const float (&v)[3][6], int bb) {
        float a0 = 0.f, a1 = 0.f, a2 = 0.f, a3 = 0.f;
#pragma unroll
        for (int k = 0; k < 3; ++k) {
#pragma unroll
            for (int l = 0; l < 3; ++l) {
                const int p = 3 * k + l;
                a0 += K[p][0] * v[k][l + 0];
                a1 += K[p][1] * v[k][l + 1];
                a2 += K[p][2] * v[k][l + 2];
                a3 += K[p][3] * v[k][l + 3];
            }
        }
        fvec4 res; res.x = a0; res.y = a1; res.z = a2; res.w = a3;
        fvec4* dst = reinterpret_cast<fvec4*>(
            out + (size_t)(b0 + bb) * N * N + (size_t)i * N + j0);
        __builtin_nontemporal_store(res, dst);
    };

    // --- issue image loads, then 2 batches of x loads (all in flight) ---
    float im[3][6];
    load_patch(image, im);

    const float* xb = x + (size_t)b0 * N * N;
    float xva[3][6], xvb[3][6];
    load_patch(xb,                    xva);   // batch b0+0
    load_patch(xb + (size_t)N * N,    xvb);   // batch b0+1

    // --- per-pixel kernels K[9][4 pixels] (waits only on image loads) ---
#pragma unroll
    for (int p = 0; p < 9; ++p) {
        const float bv = bias[p];
        float a0 = bv, a1 = bv, a2 = bv, a3 = bv;
#pragma unroll
        for (int m = 0; m < 3; ++m) {
#pragma unroll
            for (int n = 0; n < 3; ++n) {
                const float wv = w[p * 9 + m * 3 + n];
                a0 += wv * im[m][0 + n];
                a1 += wv * im[m][1 + n];
                a2 += wv * im[m][2 + n];
                a3 += wv * im[m][3 + n];
            }
        }
        K[p][0] = a0; K[p][1] = a1; K[p][2] = a2; K[p][3] = a3;
    }

    // --- pipelined apply: consume one buffer while the other loads ---
    apply_store(xva, 0);
    load_patch(xb + 2 * (size_t)N * N, xva);  // batch b0+2
    apply_store(xvb, 1);
    load_patch(xb + 3 * (size_t)N * N, xvb);  // batch b0+3
    apply_store(xva, 2);
    apply_store(xvb, 3);
}

extern "C" void kernel_launch(void* const* d_in, const int* in_sizes, int n_in,
                              void* d_out, int out_size, void* d_ws, size_t ws_size,
                              hipStream_t stream) {
    const float* image = (const float*)d_in[0];
    const float* x     = (const float*)d_in[1];
    const float* w     = (const float*)d_in[2];
    const float* bias  = (const float*)d_in[3];
    float* out = (float*)d_out;

    dim3 grid(NDIM / 64, NDIM / 16, BATCH / BCHUNK);
    dim3 block(256);
    hipLaunchKernelGGL(smallsm_fused, grid, block, 0, stream,
                       image, x, w, bias, out);
}

// Round 4
// 41.610 us; speedup vs baseline: 1.1858x; 1.1858x over previous
//
#include <hip/hip_runtime.h>

#define NDIM 1024
#define BATCH 16
#define BCHUNK 4   // batches per thread; grid.z = BATCH/BCHUNK

typedef float fvec4 __attribute__((ext_vector_type(4)));

// Raw (pre-shuffle) patch: 3 vec4 rows + edge scalars (valid on tx==0 / tx==15).
struct RawPatch {
    fvec4 m0, m1, m2;
    float l0, l1, l2;
    float r0, r1, r2;
};

// Fused spatially-varying 3x3 filter:
//   K[p,i,j] = bias[p] + sum_{m,n} w[p,0,m,n] * image_pad[i+m, j+n]
//   y[b,i,j] = sum_{k,l} K[3k+l,i,j] * x_pad[b, i+k, j+l]
// Halo columns come from neighbor lanes via shuffle (not strided scalar loads):
// a 64-lane scalar load at 64B stride touches 64 cache lines per instruction
// and was the R1/R3 bottleneck (TA line throughput), ~90% of L1 transactions.
__global__ __launch_bounds__(256, 4) void smallsm_fused(
    const float* __restrict__ image,
    const float* __restrict__ x,
    const float* __restrict__ w,
    const float* __restrict__ bias,
    float* __restrict__ out)
{
    const int N = NDIM;
    const int tx = threadIdx.x & 15;   // 16 threads in j (x4 pixels = 64 cols)
    const int ty = threadIdx.x >> 4;   // 16 threads in i
    const int j0 = (blockIdx.x * 16 + tx) * 4;
    const int i  = blockIdx.y * 16 + ty;
    const int b0 = blockIdx.z * BCHUNK;

    const bool jm_ok = (j0 > 0);
    const bool jp_ok = (j0 + 4 < N);

    // Issue loads for one 3-row patch (no shuffles, no waits consumed here).
    auto issue_patch = [&](const float* __restrict__ base, RawPatch& p) {
        fvec4 z = {0.f, 0.f, 0.f, 0.f};
        p.l0 = p.l1 = p.l2 = 0.f;
        p.r0 = p.r1 = p.r2 = 0.f;
#pragma unroll
        for (int r = 0; r < 3; ++r) {
            const int row = i - 1 + r;
            const bool rv = (row >= 0) && (row < N);
            const float* rp = base + (size_t)row * N;
            fvec4 mv = z;
            if (rv) mv = *reinterpret_cast<const fvec4*>(rp + j0);
            float lv = 0.f, rvv = 0.f;
            if (tx == 0  && rv && jm_ok) lv  = rp[j0 - 1];   // 4 lanes -> 4 lines
            if (tx == 15 && rv && jp_ok) rvv = rp[j0 + 4];   // 4 lanes -> 4 lines
            if (r == 0) { p.m0 = mv; p.l0 = lv; p.r0 = rvv; }
            if (r == 1) { p.m1 = mv; p.l1 = lv; p.r1 = rvv; }
            if (r == 2) { p.m2 = mv; p.l2 = lv; p.r2 = rvv; }
        }
    };

    // Turn a raw patch into the 3x6 window via neighbor-lane shuffles.
    auto finish_patch = [&](const RawPatch& p, float (&v)[3][6]) {
#pragma unroll
        for (int r = 0; r < 3; ++r) {
            const fvec4 m = (r == 0) ? p.m0 : (r == 1) ? p.m1 : p.m2;
            const float le = (r == 0) ? p.l0 : (r == 1) ? p.l1 : p.l2;
            const float re = (r == 0) ? p.r0 : (r == 1) ? p.r1 : p.r2;
            float left  = __shfl_up(m.w, 1);    // lane tx-1's last element
            float right = __shfl_down(m.x, 1);  // lane tx+1's first element
            if (tx == 0)  left  = le;           // crossed 16-lane row group
            if (tx == 15) right = re;
            v[r][0] = left; v[r][1] = m.x; v[r][2] = m.y;
            v[r][3] = m.z;  v[r][4] = m.w; v[r][5] = right;
        }
    };

    float K[9][4];

    auto apply_store = [&](const float (&v)[3][6], int bb) {
        float a0 = 0.f, a1 = 0.f, a2 = 0.f, a3 = 0.f;
#pragma unroll
        for (int k = 0; k < 3; ++k) {
#pragma unroll
            for (int l = 0; l < 3; ++l) {
                const int p = 3 * k + l;
                a0 += K[p][0] * v[k][l + 0];
                a1 += K[p][1] * v[k][l + 1];
                a2 += K[p][2] * v[k][l + 2];
                a3 += K[p][3] * v[k][l + 3];
            }
        }
        fvec4 res; res.x = a0; res.y = a1; res.z = a2; res.w = a3;
        fvec4* dst = reinterpret_cast<fvec4*>(
            out + (size_t)(b0 + bb) * N * N + (size_t)i * N + j0);
        __builtin_nontemporal_store(res, dst);
    };

    // --- issue image + first 2 batches (all loads in flight) ---
    const size_t NN = (size_t)N * N;
    const float* xb = x + (size_t)b0 * NN;

    RawPatch pim, pa, pb;
    issue_patch(image, pim);
    issue_patch(xb,      pa);
    issue_patch(xb + NN, pb);

    // --- per-pixel kernels K[9][4] (waits only on image loads) ---
    float im[3][6];
    finish_patch(pim, im);
#pragma unroll
    for (int p = 0; p < 9; ++p) {
        const float bv = bias[p];
        float a0 = bv, a1 = bv, a2 = bv, a3 = bv;
#pragma unroll
        for (int m = 0; m < 3; ++m) {
#pragma unroll
            for (int n = 0; n < 3; ++n) {
                const float wv = w[p * 9 + m * 3 + n];
                a0 += wv * im[m][0 + n];
                a1 += wv * im[m][1 + n];
                a2 += wv * im[m][2 + n];
                a3 += wv * im[m][3 + n];
            }
        }
        K[p][0] = a0; K[p][1] = a1; K[p][2] = a2; K[p][3] = a3;
    }

    // --- pipelined apply: consume one buffer while the other loads ---
    float va[3][6], vb[3][6];
    finish_patch(pa, va); apply_store(va, 0);
    issue_patch(xb + 2 * NN, pa);
    finish_patch(pb, vb); apply_store(vb, 1);
    issue_patch(xb + 3 * NN, pb);
    finish_patch(pa, va); apply_store(va, 2);
    finish_patch(pb, vb); apply_store(vb, 3);
}

extern "C" void kernel_launch(void* const* d_in, const int* in_sizes, int n_in,
                              void* d_out, int out_size, void* d_ws, size_t ws_size,
                              hipStream_t stream) {
    const float* image = (const float*)d_in[0];
    const float* x     = (const float*)d_in[1];
    const float* w     = (const float*)d_in[2];
    const float* bias  = (const float*)d_in[3];
    float* out = (float*)d_out;

    dim3 grid(NDIM / 64, NDIM / 16, BATCH / BCHUNK);
    dim3 block(256);
    hipLaunchKernelGGL(smallsm_fused, grid, block, 0, stream,
                       image, x, w, bias, out);
}